// Round 18
// baseline (124.279 us; speedup 1.0000x reference)
//
#include <hip/hip_runtime.h>
#include <hip/hip_bf16.h>
#include <stdint.h>

// SelfAttention1D: B=8,T=2048,D_IN=512,D_ATTN=8,D_OUT=512, scores=(QK^T)^8, softmax, @V
// k_wvT -> k_fused (QK high-precision; K in per-tile FRAGMENT layout for per-lane b128
// reads; V bf16 MFMA GEMM fragment-linear) -> k_attn: grid 256 (1/CU), 16 waves,
// ONLINE-MAX flash softmax (no prepass): scoring waves (wave g = rows [4g,4g+4),
// lane = key-pair) compute per-tile row max via shfl, emit P<=1 and per-row rescale
// factors to a dbuf LDS array; MFMA side rescales acc per tile. Q in SGPRs (rfl).
// Workspace: WvT 512K @0, Q 512K @512K, Kt 512K @1M, Vg 16M @1.5M (~17.6MB total)

typedef float f32x4_t __attribute__((ext_vector_type(4)));
typedef short s16x8_t __attribute__((ext_vector_type(8)));
typedef unsigned int u32;

static __device__ __forceinline__ unsigned short f2bf(float x){
  union { float f; u32 u; } v; v.f = x;
  return (unsigned short)((v.u + 0x7FFFu + ((v.u >> 16) & 1u)) >> 16);
}

static __device__ __forceinline__ u32 pk2bf(float a, float b){
  __hip_bfloat162 h = __float22bfloat162_rn(float2{a, b});
  union { __hip_bfloat162 h2; u32 u; } c; c.h2 = h;
  return c.u;
}

static __device__ __forceinline__ void gload16(const void* g, void* l){
  __builtin_amdgcn_global_load_lds((const __attribute__((address_space(1))) u32*)g,
                                   (__attribute__((address_space(3))) u32*)l, 16, 0, 0);
}

// force wave-uniform float into SGPR
static __device__ __forceinline__ float rfl(float x){
  return __uint_as_float(__builtin_amdgcn_readfirstlane(__float_as_uint(x)));
}

static __device__ __forceinline__ float dot8(const float* q, const float4& a, const float4& b){
  float s = q[0] * a.x;
  s = fmaf(q[1], a.y, s); s = fmaf(q[2], a.z, s); s = fmaf(q[3], a.w, s);
  s = fmaf(q[4], b.x, s); s = fmaf(q[5], b.y, s); s = fmaf(q[6], b.z, s);
  s = fmaf(q[7], b.w, s);
  return s;
}

// ---------------- K0: W_v [512][512] f32 -> WvT [c][d] bf16 ----------------
__global__ __launch_bounds__(256) void k_wvT(const float* __restrict__ Wv,
                                             unsigned short* __restrict__ WvT){
  __shared__ __align__(16) float tile[64][68];
  const int t = threadIdx.x;
  const int dbase = (blockIdx.x >> 3) * 64;
  const int cbase = (blockIdx.x & 7) * 64;
  {
    const int dl = t >> 2, cq = (t & 3) * 16;
    const float* src = Wv + (size_t)(dbase + dl) * 512 + cbase + cq;
#pragma unroll
    for (int i = 0; i < 16; i += 4){
      float4 v = *(const float4*)(src + i);
      tile[dl][cq + i + 0] = v.x; tile[dl][cq + i + 1] = v.y;
      tile[dl][cq + i + 2] = v.z; tile[dl][cq + i + 3] = v.w;
    }
  }
  __syncthreads();
  const int cl = t >> 2, dq = (t & 3) * 16;
  __align__(16) unsigned short o[16];
#pragma unroll
  for (int i = 0; i < 16; ++i) o[i] = f2bf(tile[dq + i][cl]);
  unsigned short* dst = WvT + (size_t)(cbase + cl) * 512 + dbase + dq;
  *(uint4*)dst = *(const uint4*)o;
  *(uint4*)(dst + 8) = *(const uint4*)(o + 8);
}

// ---------------- k_fused: blocks [0,1024) = Q,K ; blocks [1024,1536) = vproj ----------
// Kt float offset for (b, key, d) [per 128-key tile fragment layout]:
//   b*16384 + (key>>7)*1024 + ((key&1)*2 + (d>>2))*256 + (key>>1)*4 + (d&3)
// Vg short offset for (b, key, col):
//   b*1048576 + (key>>7)*65536 + (col>>5)*4096 + ((col>>4)&1)*2048 + ((key>>5)&3)*512
//   + (((key>>3)&3)*16 + (col&15))*8 + (key&7)
__global__ __launch_bounds__(256) void k_fused(const float* __restrict__ In,
                                               const float* __restrict__ Wq,
                                               const float* __restrict__ Wk,
                                               const unsigned short* __restrict__ WvT,
                                               float* __restrict__ Qo,
                                               float* __restrict__ Kt,
                                               unsigned short* __restrict__ Vg){
  __shared__ __align__(16) char smem[65536];
  const int t = threadIdx.x;
  if (blockIdx.x < 1024){
    float* wt = (float*)smem;                 // 32KB
    float* inT = (float*)(smem + 32768);      // 32KB
    const float* Inb = In + (size_t)blockIdx.x * 16 * 512;
#pragma unroll
    for (int i = 0; i < 8; ++i)
      gload16(Inb + (i * 256 + t) * 4, (char*)inT + (i * 256 + t) * 16);
#pragma unroll
    for (int i = 0; i < 16; i += 4){
      float4 vq = *(const float4*)(Wq + t * 16 + i);
      float4 vk = *(const float4*)(Wk + t * 16 + i);
      const float* pq = &vq.x;
      const float* pk = &vk.x;
#pragma unroll
      for (int j = 0; j < 4; ++j){
        int flat = t * 16 + i + j;
        int d = flat >> 3, f = flat & 7;
        wt[f * 512 + ((((d >> 2) ^ f) << 2) | (d & 3))] = pq[j];
        int fk = f + 8;
        wt[fk * 512 + ((((d >> 2) ^ (fk & 7)) << 2) | (d & 3))] = pk[j];
      }
    }
    __syncthreads();
    const int tokl = t >> 4;
    const int f = t & 15;
    const float* inrow = inT + tokl * 512;
    const float* wrow = &wt[f * 512];
    const int swz = f & 7;
    double acc = 0.0;
    for (int cb = 0; cb < 128; cb += 8){
      float part = 0.f;
#pragma unroll
      for (int c = cb; c < cb + 8; ++c){
        float4 x = *(const float4*)(inrow + c * 4);
        float4 ww = *(const float4*)(wrow + ((c ^ swz) << 2));
        part = fmaf(x.x, ww.x, part); part = fmaf(x.y, ww.y, part);
        part = fmaf(x.z, ww.z, part); part = fmaf(x.w, ww.w, part);
      }
      acc += (double)part;
    }
    float r = (float)acc;
    const int tok = (int)blockIdx.x * 16 + tokl;
    if (f < 8) Qo[(size_t)tok * 8 + f] = r;
    else {
      const int bq = tok >> 11, kk = tok & 2047;
      const int key = kk & 127, d = f - 8;
      Kt[(size_t)bq * 16384 + (size_t)(kk >> 7) * 1024
         + ((key & 1) * 2 + (d >> 2)) * 256 + (key >> 1) * 4 + (d & 3)] = r;
    }
    return;
  }
  // ---- vproj part ----
  char* Ab = smem;
  char* Bb = smem + 16384;
  char* Img = smem + 32768;
  const int vb = (int)blockIdx.x - 1024;
  const int w = t >> 6, lane = t & 63;
  const int mt = vb >> 2, nt = vb & 3;
  const int wm = w >> 1, wn = w & 1;
  const int asub = lane & 3;
  int arow[2], acr[2];
#pragma unroll
  for (int i = 0; i < 2; ++i){
    arow[i] = (w * 2 + i) * 16 + (lane >> 2);
    acr[i]  = asub ^ ((arow[i] >> 1) & 3);
  }
  f32x4_t acc[4][4];
#pragma unroll
  for (int m = 0; m < 4; ++m)
#pragma unroll
    for (int n = 0; n < 4; ++n)
      acc[m][n] = (f32x4_t){0.f, 0.f, 0.f, 0.f};

  auto stageB = [&](int kk, int sel){
#pragma unroll
    for (int i = 0; i < 2; ++i){
      int id = w * 2 + i;
      const unsigned short* gb = WvT + (size_t)(nt * 128 + arow[i]) * 512 + kk * 32 + acr[i] * 8;
      gload16(gb, Bb + sel * 8192 + id * 1024);
    }
  };
  auto loadA = [&](int kk, float4* x, float4* y){
#pragma unroll
    for (int i = 0; i < 2; ++i){
      const float* ga = In + (size_t)(mt * 128 + arow[i]) * 512 + kk * 32 + acr[i] * 8;
      x[i] = *(const float4*)ga;
      y[i] = *(const float4*)(ga + 4);
    }
  };
  auto writeA = [&](const float4* x, const float4* y, int sel){
#pragma unroll
    for (int i = 0; i < 2; ++i){
      __align__(16) unsigned short pk[8] = {
        f2bf(x[i].x), f2bf(x[i].y), f2bf(x[i].z), f2bf(x[i].w),
        f2bf(y[i].x), f2bf(y[i].y), f2bf(y[i].z), f2bf(y[i].w)};
      *(uint4*)(Ab + sel * 8192 + arow[i] * 64 + asub * 16) = *(const uint4*)pk;
    }
  };
  {
    float4 x[2], y[2];
    loadA(0, x, y);
    stageB(0, 0);
    writeA(x, y, 0);
    __syncthreads();
  }
  for (int kk = 0; kk < 16; ++kk){
    const int cur = kk & 1;
    float4 x[2], y[2];
    if (kk < 15){
      loadA(kk + 1, x, y);
      stageB(kk + 1, cur ^ 1);
    }
    s16x8_t a[4], bf[4];
#pragma unroll
    for (int m = 0; m < 4; ++m){
      int row = wm * 64 + m * 16 + (lane & 15);
      int chn = (lane >> 4) ^ ((row >> 1) & 3);
      a[m] = *(const s16x8_t*)(Ab + cur * 8192 + row * 64 + chn * 16);
    }
#pragma unroll
    for (int n = 0; n < 4; ++n){
      int col = wn * 64 + n * 16 + (lane & 15);
      int chn = (lane >> 4) ^ ((col >> 1) & 3);
      bf[n] = *(const s16x8_t*)(Bb + cur * 8192 + col * 64 + chn * 16);
    }
#pragma unroll
    for (int m = 0; m < 4; ++m)
#pragma unroll
      for (int n = 0; n < 4; ++n)
        acc[m][n] = __builtin_amdgcn_mfma_f32_16x16x32_bf16(a[m], bf[n], acc[m][n], 0, 0, 0);
    if (kk < 15) writeA(x, y, cur ^ 1);
    __syncthreads();
  }
#pragma unroll
  for (int m = 0; m < 4; ++m){
    const int ks2 = (wm * 2 + (m >> 1)) & 3;
    const int hi  = (m * 2 + ((lane >> 4) >> 1)) & 3;
    const int lo0 = ((lane >> 4) & 1) * 4;
#pragma unroll
    for (int n = 0; n < 4; ++n){
      const int g_loc = wn * 2 + (n >> 1);
      const int n2 = n & 1;
      const int cl = lane & 15;
      __align__(8) unsigned short pk2[4];
#pragma unroll
      for (int j = 0; j < 4; ++j) pk2[j] = f2bf(acc[m][n][j]);
      int boff = g_loc * 8192 + n2 * 4096 + ks2 * 1024 + hi * 256 + cl * 16 + lo0 * 2;
      *(uint2*)(Img + boff) = *(const uint2*)pk2;
    }
  }
  __syncthreads();
  const int bq = mt >> 4;
  const int kt = mt & 15;
#pragma unroll
  for (int i = 0; i < 8; ++i){
    int G = i * 256 + t;
    unsigned short* dst = Vg + (size_t)bq * 1048576 + (size_t)kt * 65536
                        + nt * 16384 + G * 8;
    *(uint4*)dst = *(const uint4*)(Img + G * 16);
  }
}

// ---------------- k_attn: 64-row x 512-col blocks, grid 256 (1/CU), 16 waves ----------------
// Online-max flash softmax, no prepass. Scoring: wave g rows [4g,4g+4), lane = key-pair.
__global__ __launch_bounds__(1024) void k_attn(const float* __restrict__ Qg,
                                               const float* __restrict__ Kt,
                                               const unsigned short* __restrict__ Vg,
                                               float* __restrict__ Out){
  __shared__ __align__(16) char smem[99072];
  // Klds 64KB @0 ; Pb dbuf 2x16KB @65536 ; fac dbuf 2x64 f32 @98304 ; fin 64 f32 @98816
  // epilogue img [16][520] f32 @0 overlays Klds
  const int t = threadIdx.x;
  const int g = t >> 6, lane = t & 63;
  const int b = blockIdx.x & 7;
  const int qt = blockIdx.x >> 3;
  const int qbase = qt * 64;

  // q for this wave's 4 score-rows — wave-uniform -> SGPRs via readfirstlane
  float q4[4][8];
#pragma unroll
  for (int rr = 0; rr < 4; ++rr){
    const float* Qp = Qg + (size_t)(b * 2048 + qbase + g * 4 + rr) * 8;
    float4 a = *(const float4*)Qp;
    float4 c = *(const float4*)(Qp + 4);
    q4[rr][0] = rfl(a.x); q4[rr][1] = rfl(a.y); q4[rr][2] = rfl(a.z); q4[rr][3] = rfl(a.w);
    q4[rr][4] = rfl(c.x); q4[rr][5] = rfl(c.y); q4[rr][6] = rfl(c.z); q4[rr][7] = rfl(c.w);
  }
  const float* Kp = Kt + (size_t)b * 16384;
  const unsigned short* Vb = Vg + (size_t)b * 1048576;
  char* Klds = smem;
  char* Pb = smem + 65536;
  float* facLds = (float*)(smem + 98304);
  float* fin = (float*)(smem + 98816);

  // ---- stage ALL of K (64KB, fragment-layout tiles) once ----
#pragma unroll
  for (int i = 0; i < 4; ++i)
    gload16(Kp + (size_t)(i * 1024 + t) * 4, Klds + (i * 1024 + t) * 16);
  __syncthreads();

  const float LOG2E = 1.44269504f;
  float m0 = 0.f, m1 = 0.f, m2 = 0.f, m3 = 0.f;       // running row max of p (p >= 0)
  float lp0 = 0.f, lp1 = 0.f, lp2 = 0.f, lp3 = 0.f;

  f32x4_t acc[4][2];
#pragma unroll
  for (int mm = 0; mm < 4; ++mm)
#pragma unroll
    for (int n = 0; n < 2; ++n)
      acc[mm][n] = (f32x4_t){0.f, 0.f, 0.f, 0.f};

  // score one row rr of a tile: online-max update, P write, factor write
  auto scoreRow = [&](int rr, float& m_rr, float& lpr,
                      const float4& r0, const float4& r1,
                      const float4& r2, const float4& r3, int sel){
    float s0 = dot8(q4[rr], r0, r1), s1 = dot8(q4[rr], r2, r3);
    float p0, p1;
    { float a2 = s0 * s0; float a4 = a2 * a2; p0 = a4 * a4; }
    { float a2 = s1 * s1; float a4 = a2 * a2; p1 = a4 * a4; }
    float pm = fmaxf(p0, p1);
#pragma unroll
    for (int sh = 1; sh < 64; sh <<= 1) pm = fmaxf(pm, __shfl_xor(pm, sh));
    float newm = rfl(fmaxf(m_rr, pm));
    float f = __builtin_amdgcn_exp2f((m_rr - newm) * LOG2E);   // <= 1
    m_rr = newm;
    float nm = newm * LOG2E;
    float e0 = __builtin_amdgcn_exp2f(fmaf(p0, LOG2E, -nm));
    float e1 = __builtin_amdgcn_exp2f(fmaf(p1, LOG2E, -nm));
    lpr = fmaf(lpr, f, e0 + e1);
    const int row = g * 4 + rr;
    if (lane == 0) facLds[sel * 64 + row] = f;
    *(u32*)(Pb + sel * 16384 + row * 256
            + ((((lane >> 2) ^ (row & 15))) << 4) + (lane & 3) * 4) = pk2bf(e0, e1);
  };

  // prologue: score tile 0 fully into Pb[0] / fac[0]
  {
    const float* kb = (const float*)Klds + lane * 4;
    float4 r0 = *(const float4*)(kb);
    float4 r1 = *(const float4*)(kb + 256);
    float4 r2 = *(const float4*)(kb + 512);
    float4 r3 = *(const float4*)(kb + 768);
    scoreRow(0, m0, lp0, r0, r1, r2, r3, 0);
    scoreRow(1, m1, lp1, r0, r1, r2, r3, 0);
    scoreRow(2, m2, lp2, r0, r1, r2, r3, 0);
    scoreRow(3, m3, lp3, r0, r1, r2, r3, 0);
  }
  __syncthreads();

  // ---- main loop: per tile: rescale acc, interleave {1-row score | a-frags | 8 MFMA} x4 ----
  for (int tt = 0; tt < 16; ++tt){
    const int sel = tt & 1;
    s16x8_t vf[2][4];
    {
      const unsigned short* vb = Vb + (size_t)tt * 65536 + g * 4096 + lane * 8;
#pragma unroll
      for (int n = 0; n < 2; ++n)
#pragma unroll
        for (int ks = 0; ks < 4; ++ks)
          vf[n][ks] = *(const s16x8_t*)(vb + n * 2048 + ks * 512);
    }
    // rescale acc by this tile's row factors
#pragma unroll
    for (int mm = 0; mm < 4; ++mm){
      int r0w = mm * 16 + ((lane >> 4) << 2);
      float4 fc = *(const float4*)(facLds + sel * 64 + r0w);
      const float* fp = &fc.x;
#pragma unroll
      for (int j = 0; j < 4; ++j)
#pragma unroll
        for (int n = 0; n < 2; ++n)
          acc[mm][n][j] *= fp[j];
    }
    const bool more = (tt + 1 < 16);
    float4 r0, r1, r2, r3;
    if (more){
      const float* kb = (const float*)Klds + ((tt + 1) & 15) * 1024 + lane * 4;
      r0 = *(const float4*)(kb);
      r1 = *(const float4*)(kb + 256);
      r2 = *(const float4*)(kb + 512);
      r3 = *(const float4*)(kb + 768);
    }
#pragma unroll
    for (int ks = 0; ks < 4; ++ks){
      if (more){
        if (ks == 0) scoreRow(0, m0, lp0, r0, r1, r2, r3, sel ^ 1);
        if (ks == 1) scoreRow(1, m1, lp1, r0, r1, r2, r3, sel ^ 1);
        if (ks == 2) scoreRow(2, m2, lp2, r0, r1, r2, r3, sel ^ 1);
        if (ks == 3) scoreRow(3, m3, lp3, r0, r1, r2, r3, sel ^ 1);
      }
      s16x8_t a[4];
#pragma unroll
      for (int mm = 0; mm < 4; ++mm){
        int r = mm * 16 + (lane & 15);
        int slot = (ks * 4 + (lane >> 4)) ^ (r & 15);
        a[mm] = *(const s16x8_t*)(Pb + sel * 16384 + r * 256 + (slot << 4));
      }
      __builtin_amdgcn_s_setprio(1);
#pragma unroll
      for (int mm = 0; mm < 4; ++mm)
#pragma unroll
        for (int n = 0; n < 2; ++n)
          acc[mm][n] = __builtin_amdgcn_mfma_f32_16x16x32_bf16(a[mm], vf[n][ks], acc[mm][n], 0, 0, 0);
      __builtin_amdgcn_s_setprio(0);
    }
    __syncthreads();
  }

  // ---- softmax denominator: in-wave shfl sums, wave owns rows [4g,4g+4) ----
#pragma unroll
  for (int sh = 1; sh < 64; sh <<= 1){
    lp0 += __shfl_xor(lp0, sh);
    lp1 += __shfl_xor(lp1, sh);
    lp2 += __shfl_xor(lp2, sh);
    lp3 += __shfl_xor(lp3, sh);
  }
  if (lane == 0){
    fin[g * 4 + 0] = 1.f / lp0;
    fin[g * 4 + 1] = 1.f / lp1;
    fin[g * 4 + 2] = 1.f / lp2;
    fin[g * 4 + 3] = 1.f / lp3;
  }
  __syncthreads();

  // ---- epilogue: 4 rounds of 16 rows x 512 cols via LDS transpose (img overlays Klds) ----
  float* img = (float*)smem;
#pragma unroll
  for (int mm = 0; mm < 4; ++mm){
    float linv[4];
#pragma unroll
    for (int j = 0; j < 4; ++j)
      linv[j] = fin[mm * 16 + ((lane >> 4) << 2) + j];
#pragma unroll
    for (int n = 0; n < 2; ++n){
      int colL = g * 32 + n * 16 + (lane & 15);
#pragma unroll
      for (int j = 0; j < 4; ++j){
        int r16 = ((lane >> 4) << 2) + j;
        img[r16 * 520 + colL] = acc[mm][n][j] * linv[j];
      }
    }
    __syncthreads();
#pragma unroll
    for (int i = 0; i < 2; ++i){
      int f4 = i * 1024 + t;
      int r16 = f4 >> 7, c4 = f4 & 127;
      float4 v = *(const float4*)(img + r16 * 520 + c4 * 4);
      *(float4*)(Out + (size_t)(b * 2048 + qbase + mm * 16 + r16) * 512 + c4 * 4) = v;
    }
    __syncthreads();
  }
}

extern "C" void kernel_launch(void* const* d_in, const int* in_sizes, int n_in,
                              void* d_out, int out_size, void* d_ws, size_t ws_size,
                              hipStream_t stream){
  const float* In = (const float*)d_in[0];
  const float* Wq = (const float*)d_in[1];
  const float* Wk = (const float*)d_in[2];
  const float* Wv = (const float*)d_in[3];
  // power (d_in[4]) is the constant 8; hardcoded as three squarings.
  char* ws = (char*)d_ws;
  unsigned short* WvT = (unsigned short*)(ws);
  float* Q            = (float*)(ws + 524288);
  float* Kt           = (float*)(ws + 1048576);
  unsigned short* Vg  = (unsigned short*)(ws + 1572864);
  float* Out = (float*)d_out;

  hipLaunchKernelGGL(k_wvT,   dim3(64),   dim3(256),  0, stream, Wv, WvT);
  hipLaunchKernelGGL(k_fused, dim3(1536), dim3(256),  0, stream, In, Wq, Wk, WvT, Q, Kt, Vg);
  hipLaunchKernelGGL(k_attn,  dim3(256),  dim3(1024), 0, stream, Q, Kt, Vg, Out);
}

// Round 19
// 97.714 us; speedup vs baseline: 1.2719x; 1.2719x over previous
//
#include <hip/hip_runtime.h>
#include <hip/hip_bf16.h>
#include <stdint.h>

// SelfAttention1D: B=8,T=2048,D_IN=512,D_ATTN=8,D_OUT=512, scores=(QK^T)^8, softmax, @V
// ROUND-17 REVERT (best verified: 97.99 us total; r18's online-max regressed).
// k_wvT -> k_fused (QK high-precision; K in per-tile FRAGMENT layout for per-lane b128
// reads; V bf16 MFMA GEMM fragment-linear) -> k_attn: grid 256 (1/CU), 16 waves.
// Flipped score mapping (wave g scores rows [4g,4g+4), lane = key-pair) with wave-uniform
// Q and row-max constants forced into SGPRs via readfirstlane (no scratch spills).
// Workspace: WvT 512K @0, Q 512K @512K, Kt 512K @1M, Vg 16M @1.5M (~17.6MB total)

typedef float f32x4_t __attribute__((ext_vector_type(4)));
typedef short s16x8_t __attribute__((ext_vector_type(8)));
typedef unsigned int u32;

static __device__ __forceinline__ unsigned short f2bf(float x){
  union { float f; u32 u; } v; v.f = x;
  return (unsigned short)((v.u + 0x7FFFu + ((v.u >> 16) & 1u)) >> 16);
}

static __device__ __forceinline__ u32 pk2bf(float a, float b){
  __hip_bfloat162 h = __float22bfloat162_rn(float2{a, b});
  union { __hip_bfloat162 h2; u32 u; } c; c.h2 = h;
  return c.u;
}

static __device__ __forceinline__ void gload16(const void* g, void* l){
  __builtin_amdgcn_global_load_lds((const __attribute__((address_space(1))) u32*)g,
                                   (__attribute__((address_space(3))) u32*)l, 16, 0, 0);
}

// force wave-uniform float into SGPR
static __device__ __forceinline__ float rfl(float x){
  return __uint_as_float(__builtin_amdgcn_readfirstlane(__float_as_uint(x)));
}

static __device__ __forceinline__ float dot8(const float* q, const float4& a, const float4& b){
  float s = q[0] * a.x;
  s = fmaf(q[1], a.y, s); s = fmaf(q[2], a.z, s); s = fmaf(q[3], a.w, s);
  s = fmaf(q[4], b.x, s); s = fmaf(q[5], b.y, s); s = fmaf(q[6], b.z, s);
  s = fmaf(q[7], b.w, s);
  return s;
}

// ---------------- K0: W_v [512][512] f32 -> WvT [c][d] bf16 ----------------
__global__ __launch_bounds__(256) void k_wvT(const float* __restrict__ Wv,
                                             unsigned short* __restrict__ WvT){
  __shared__ __align__(16) float tile[64][68];
  const int t = threadIdx.x;
  const int dbase = (blockIdx.x >> 3) * 64;
  const int cbase = (blockIdx.x & 7) * 64;
  {
    const int dl = t >> 2, cq = (t & 3) * 16;
    const float* src = Wv + (size_t)(dbase + dl) * 512 + cbase + cq;
#pragma unroll
    for (int i = 0; i < 16; i += 4){
      float4 v = *(const float4*)(src + i);
      tile[dl][cq + i + 0] = v.x; tile[dl][cq + i + 1] = v.y;
      tile[dl][cq + i + 2] = v.z; tile[dl][cq + i + 3] = v.w;
    }
  }
  __syncthreads();
  const int cl = t >> 2, dq = (t & 3) * 16;
  __align__(16) unsigned short o[16];
#pragma unroll
  for (int i = 0; i < 16; ++i) o[i] = f2bf(tile[dq + i][cl]);
  unsigned short* dst = WvT + (size_t)(cbase + cl) * 512 + dbase + dq;
  *(uint4*)dst = *(const uint4*)o;
  *(uint4*)(dst + 8) = *(const uint4*)(o + 8);
}

// ---------------- k_fused: blocks [0,1024) = Q,K ; blocks [1024,1536) = vproj ----------
// Kt float offset for (b, key, d) [per 128-key tile fragment layout]:
//   b*16384 + (key>>7)*1024 + ((key&1)*2 + (d>>2))*256 + (key>>1)*4 + (d&3)
// Vg short offset for (b, key, col):
//   b*1048576 + (key>>7)*65536 + (col>>5)*4096 + ((col>>4)&1)*2048 + ((key>>5)&3)*512
//   + (((key>>3)&3)*16 + (col&15))*8 + (key&7)
__global__ __launch_bounds__(256) void k_fused(const float* __restrict__ In,
                                               const float* __restrict__ Wq,
                                               const float* __restrict__ Wk,
                                               const unsigned short* __restrict__ WvT,
                                               float* __restrict__ Qo,
                                               float* __restrict__ Kt,
                                               unsigned short* __restrict__ Vg){
  __shared__ __align__(16) char smem[65536];
  const int t = threadIdx.x;
  if (blockIdx.x < 1024){
    float* wt = (float*)smem;                 // 32KB
    float* inT = (float*)(smem + 32768);      // 32KB
    const float* Inb = In + (size_t)blockIdx.x * 16 * 512;
#pragma unroll
    for (int i = 0; i < 8; ++i)
      gload16(Inb + (i * 256 + t) * 4, (char*)inT + (i * 256 + t) * 16);
#pragma unroll
    for (int i = 0; i < 16; i += 4){
      float4 vq = *(const float4*)(Wq + t * 16 + i);
      float4 vk = *(const float4*)(Wk + t * 16 + i);
      const float* pq = &vq.x;
      const float* pk = &vk.x;
#pragma unroll
      for (int j = 0; j < 4; ++j){
        int flat = t * 16 + i + j;
        int d = flat >> 3, f = flat & 7;
        wt[f * 512 + ((((d >> 2) ^ f) << 2) | (d & 3))] = pq[j];
        int fk = f + 8;
        wt[fk * 512 + ((((d >> 2) ^ (fk & 7)) << 2) | (d & 3))] = pk[j];
      }
    }
    __syncthreads();
    const int tokl = t >> 4;
    const int f = t & 15;
    const float* inrow = inT + tokl * 512;
    const float* wrow = &wt[f * 512];
    const int swz = f & 7;
    double acc = 0.0;
    for (int cb = 0; cb < 128; cb += 8){
      float part = 0.f;
#pragma unroll
      for (int c = cb; c < cb + 8; ++c){
        float4 x = *(const float4*)(inrow + c * 4);
        float4 ww = *(const float4*)(wrow + ((c ^ swz) << 2));
        part = fmaf(x.x, ww.x, part); part = fmaf(x.y, ww.y, part);
        part = fmaf(x.z, ww.z, part); part = fmaf(x.w, ww.w, part);
      }
      acc += (double)part;
    }
    float r = (float)acc;
    const int tok = (int)blockIdx.x * 16 + tokl;
    if (f < 8) Qo[(size_t)tok * 8 + f] = r;
    else {
      const int bq = tok >> 11, kk = tok & 2047;
      const int key = kk & 127, d = f - 8;
      Kt[(size_t)bq * 16384 + (size_t)(kk >> 7) * 1024
         + ((key & 1) * 2 + (d >> 2)) * 256 + (key >> 1) * 4 + (d & 3)] = r;
    }
    return;
  }
  // ---- vproj part ----
  char* Ab = smem;
  char* Bb = smem + 16384;
  char* Img = smem + 32768;
  const int vb = (int)blockIdx.x - 1024;
  const int w = t >> 6, lane = t & 63;
  const int mt = vb >> 2, nt = vb & 3;
  const int wm = w >> 1, wn = w & 1;
  const int asub = lane & 3;
  int arow[2], acr[2];
#pragma unroll
  for (int i = 0; i < 2; ++i){
    arow[i] = (w * 2 + i) * 16 + (lane >> 2);
    acr[i]  = asub ^ ((arow[i] >> 1) & 3);
  }
  f32x4_t acc[4][4];
#pragma unroll
  for (int m = 0; m < 4; ++m)
#pragma unroll
    for (int n = 0; n < 4; ++n)
      acc[m][n] = (f32x4_t){0.f, 0.f, 0.f, 0.f};

  auto stageB = [&](int kk, int sel){
#pragma unroll
    for (int i = 0; i < 2; ++i){
      int id = w * 2 + i;
      const unsigned short* gb = WvT + (size_t)(nt * 128 + arow[i]) * 512 + kk * 32 + acr[i] * 8;
      gload16(gb, Bb + sel * 8192 + id * 1024);
    }
  };
  auto loadA = [&](int kk, float4* x, float4* y){
#pragma unroll
    for (int i = 0; i < 2; ++i){
      const float* ga = In + (size_t)(mt * 128 + arow[i]) * 512 + kk * 32 + acr[i] * 8;
      x[i] = *(const float4*)ga;
      y[i] = *(const float4*)(ga + 4);
    }
  };
  auto writeA = [&](const float4* x, const float4* y, int sel){
#pragma unroll
    for (int i = 0; i < 2; ++i){
      __align__(16) unsigned short pk[8] = {
        f2bf(x[i].x), f2bf(x[i].y), f2bf(x[i].z), f2bf(x[i].w),
        f2bf(y[i].x), f2bf(y[i].y), f2bf(y[i].z), f2bf(y[i].w)};
      *(uint4*)(Ab + sel * 8192 + arow[i] * 64 + asub * 16) = *(const uint4*)pk;
    }
  };
  {
    float4 x[2], y[2];
    loadA(0, x, y);
    stageB(0, 0);
    writeA(x, y, 0);
    __syncthreads();
  }
  for (int kk = 0; kk < 16; ++kk){
    const int cur = kk & 1;
    float4 x[2], y[2];
    if (kk < 15){
      loadA(kk + 1, x, y);
      stageB(kk + 1, cur ^ 1);
    }
    s16x8_t a[4], bf[4];
#pragma unroll
    for (int m = 0; m < 4; ++m){
      int row = wm * 64 + m * 16 + (lane & 15);
      int chn = (lane >> 4) ^ ((row >> 1) & 3);
      a[m] = *(const s16x8_t*)(Ab + cur * 8192 + row * 64 + chn * 16);
    }
#pragma unroll
    for (int n = 0; n < 4; ++n){
      int col = wn * 64 + n * 16 + (lane & 15);
      int chn = (lane >> 4) ^ ((col >> 1) & 3);
      bf[n] = *(const s16x8_t*)(Bb + cur * 8192 + col * 64 + chn * 16);
    }
#pragma unroll
    for (int m = 0; m < 4; ++m)
#pragma unroll
      for (int n = 0; n < 4; ++n)
        acc[m][n] = __builtin_amdgcn_mfma_f32_16x16x32_bf16(a[m], bf[n], acc[m][n], 0, 0, 0);
    if (kk < 15) writeA(x, y, cur ^ 1);
    __syncthreads();
  }
#pragma unroll
  for (int m = 0; m < 4; ++m){
    const int ks2 = (wm * 2 + (m >> 1)) & 3;
    const int hi  = (m * 2 + ((lane >> 4) >> 1)) & 3;
    const int lo0 = ((lane >> 4) & 1) * 4;
#pragma unroll
    for (int n = 0; n < 4; ++n){
      const int g_loc = wn * 2 + (n >> 1);
      const int n2 = n & 1;
      const int cl = lane & 15;
      __align__(8) unsigned short pk2[4];
#pragma unroll
      for (int j = 0; j < 4; ++j) pk2[j] = f2bf(acc[m][n][j]);
      int boff = g_loc * 8192 + n2 * 4096 + ks2 * 1024 + hi * 256 + cl * 16 + lo0 * 2;
      *(uint2*)(Img + boff) = *(const uint2*)pk2;
    }
  }
  __syncthreads();
  const int bq = mt >> 4;
  const int kt = mt & 15;
#pragma unroll
  for (int i = 0; i < 8; ++i){
    int G = i * 256 + t;
    unsigned short* dst = Vg + (size_t)bq * 1048576 + (size_t)kt * 65536
                        + nt * 16384 + G * 8;
    *(uint4*)dst = *(const uint4*)(Img + G * 16);
  }
}

// ---------------- k_attn: 64-row x 512-col blocks, grid 256 (1/CU), 16 waves ----------------
// Flipped score mapping; wave-uniform Q/nme2 in SGPRs (readfirstlane) to avoid spills.
__global__ __launch_bounds__(1024) void k_attn(const float* __restrict__ Qg,
                                               const float* __restrict__ Kt,
                                               const unsigned short* __restrict__ Vg,
                                               float* __restrict__ Out){
  __shared__ __align__(16) char smem[102656];
  // Klds 64KB @0 ; Pb dbuf 2x16KB @65536 ; fin 256B @102400
  // epilogue img [16][520] f32 @0 overlays Klds
  const int t = threadIdx.x;
  const int g = t >> 6, lane = t & 63;
  const int b = blockIdx.x & 7;
  const int qt = blockIdx.x >> 3;
  const int qbase = qt * 64;

  // q for this wave's 4 score-rows — wave-uniform -> SGPRs via readfirstlane
  float q4[4][8];
#pragma unroll
  for (int rr = 0; rr < 4; ++rr){
    const float* Qp = Qg + (size_t)(b * 2048 + qbase + g * 4 + rr) * 8;
    float4 a = *(const float4*)Qp;
    float4 c = *(const float4*)(Qp + 4);
    q4[rr][0] = rfl(a.x); q4[rr][1] = rfl(a.y); q4[rr][2] = rfl(a.z); q4[rr][3] = rfl(a.w);
    q4[rr][4] = rfl(c.x); q4[rr][5] = rfl(c.y); q4[rr][6] = rfl(c.z); q4[rr][7] = rfl(c.w);
  }
  const float* Kp = Kt + (size_t)b * 16384;
  const unsigned short* Vb = Vg + (size_t)b * 1048576;
  char* Klds = smem;
  char* Pb = smem + 65536;
  float* fin = (float*)(smem + 102400);

  // ---- stage ALL of K (64KB, fragment-layout tiles) once ----
#pragma unroll
  for (int i = 0; i < 4; ++i)
    gload16(Kp + (size_t)(i * 1024 + t) * 4, Klds + (i * 1024 + t) * 16);
  __syncthreads();

  // ---- prepass: row max of s^2 over this lane's 2 keys x 16 tiles, then wave shfl-max ----
  float mx0 = 0.f, mx1 = 0.f, mx2 = 0.f, mx3 = 0.f;
  {
    const float* kbase = (const float*)Klds + lane * 4;
#pragma unroll 2
    for (int tt = 0; tt < 16; ++tt){
      const float* kb = kbase + tt * 1024;
      float4 r0 = *(const float4*)(kb);
      float4 r1 = *(const float4*)(kb + 256);
      float4 r2 = *(const float4*)(kb + 512);
      float4 r3 = *(const float4*)(kb + 768);
      {
        float s0 = dot8(q4[0], r0, r1), s1 = dot8(q4[0], r2, r3);
        mx0 = fmaxf(mx0, fmaxf(s0 * s0, s1 * s1));
      }
      {
        float s0 = dot8(q4[1], r0, r1), s1 = dot8(q4[1], r2, r3);
        mx1 = fmaxf(mx1, fmaxf(s0 * s0, s1 * s1));
      }
      {
        float s0 = dot8(q4[2], r0, r1), s1 = dot8(q4[2], r2, r3);
        mx2 = fmaxf(mx2, fmaxf(s0 * s0, s1 * s1));
      }
      {
        float s0 = dot8(q4[3], r0, r1), s1 = dot8(q4[3], r2, r3);
        mx3 = fmaxf(mx3, fmaxf(s0 * s0, s1 * s1));
      }
    }
  }
#pragma unroll
  for (int sh = 1; sh < 64; sh <<= 1){
    mx0 = fmaxf(mx0, __shfl_xor(mx0, sh));
    mx1 = fmaxf(mx1, __shfl_xor(mx1, sh));
    mx2 = fmaxf(mx2, __shfl_xor(mx2, sh));
    mx3 = fmaxf(mx3, __shfl_xor(mx3, sh));
  }
  const float LOG2E = 1.44269504f;
  // wave-uniform after reduction -> SGPRs
  float nme2_0, nme2_1, nme2_2, nme2_3;
  { float s4 = mx0 * mx0; nme2_0 = rfl(-(s4 * s4) * LOG2E); }
  { float s4 = mx1 * mx1; nme2_1 = rfl(-(s4 * s4) * LOG2E); }
  { float s4 = mx2 * mx2; nme2_2 = rfl(-(s4 * s4) * LOG2E); }
  { float s4 = mx3 * mx3; nme2_3 = rfl(-(s4 * s4) * LOG2E); }
  float lp0 = 0.f, lp1 = 0.f, lp2 = 0.f, lp3 = 0.f;

  f32x4_t acc[4][2];
#pragma unroll
  for (int mm = 0; mm < 4; ++mm)
#pragma unroll
    for (int n = 0; n < 2; ++n)
      acc[mm][n] = (f32x4_t){0.f, 0.f, 0.f, 0.f};

  // score one row rr of a tile (K regs passed in), write one P word
  auto scoreRow = [&](int rr, float nme2r, float& lpr,
                      const float4& r0, const float4& r1,
                      const float4& r2, const float4& r3, int sel){
    float s0 = dot8(q4[rr], r0, r1), s1 = dot8(q4[rr], r2, r3);
    float p0, p1;
    { float a2 = s0 * s0; float a4 = a2 * a2; p0 = a4 * a4; }
    { float a2 = s1 * s1; float a4 = a2 * a2; p1 = a4 * a4; }
    float e0 = __builtin_amdgcn_exp2f(fmaf(p0, LOG2E, nme2r));
    float e1 = __builtin_amdgcn_exp2f(fmaf(p1, LOG2E, nme2r));
    lpr += e0 + e1;
    const int row = g * 4 + rr;
    *(u32*)(Pb + sel * 16384 + row * 256
            + ((((lane >> 2) ^ (row & 15))) << 4) + (lane & 3) * 4) = pk2bf(e0, e1);
  };

  // prologue: score tile 0 fully into Pb[0]
  {
    const float* kb = (const float*)Klds + lane * 4;
    float4 r0 = *(const float4*)(kb);
    float4 r1 = *(const float4*)(kb + 256);
    float4 r2 = *(const float4*)(kb + 512);
    float4 r3 = *(const float4*)(kb + 768);
    scoreRow(0, nme2_0, lp0, r0, r1, r2, r3, 0);
    scoreRow(1, nme2_1, lp1, r0, r1, r2, r3, 0);
    scoreRow(2, nme2_2, lp2, r0, r1, r2, r3, 0);
    scoreRow(3, nme2_3, lp3, r0, r1, r2, r3, 0);
  }
  __syncthreads();

  // ---- main loop: per tile, interleave {1-row score | a-frags | 8 MFMA} x4 ----
  for (int tt = 0; tt < 16; ++tt){
    const int sel = tt & 1;
    s16x8_t vf[2][4];
    {
      const unsigned short* vb = Vb + (size_t)tt * 65536 + g * 4096 + lane * 8;
#pragma unroll
      for (int n = 0; n < 2; ++n)
#pragma unroll
        for (int ks = 0; ks < 4; ++ks)
          vf[n][ks] = *(const s16x8_t*)(vb + n * 2048 + ks * 512);
    }
    const bool more = (tt + 1 < 16);
    float4 r0, r1, r2, r3;
    if (more){
      const float* kb = (const float*)Klds + ((tt + 1) & 15) * 1024 + lane * 4;
      r0 = *(const float4*)(kb);
      r1 = *(const float4*)(kb + 256);
      r2 = *(const float4*)(kb + 512);
      r3 = *(const float4*)(kb + 768);
    }
#pragma unroll
    for (int ks = 0; ks < 4; ++ks){
      if (more){
        if (ks == 0) scoreRow(0, nme2_0, lp0, r0, r1, r2, r3, sel ^ 1);
        if (ks == 1) scoreRow(1, nme2_1, lp1, r0, r1, r2, r3, sel ^ 1);
        if (ks == 2) scoreRow(2, nme2_2, lp2, r0, r1, r2, r3, sel ^ 1);
        if (ks == 3) scoreRow(3, nme2_3, lp3, r0, r1, r2, r3, sel ^ 1);
      }
      s16x8_t a[4];
#pragma unroll
      for (int mm = 0; mm < 4; ++mm){
        int r = mm * 16 + (lane & 15);
        int slot = (ks * 4 + (lane >> 4)) ^ (r & 15);
        a[mm] = *(const s16x8_t*)(Pb + sel * 16384 + r * 256 + (slot << 4));
      }
      __builtin_amdgcn_s_setprio(1);
#pragma unroll
      for (int mm = 0; mm < 4; ++mm)
#pragma unroll
        for (int n = 0; n < 2; ++n)
          acc[mm][n] = __builtin_amdgcn_mfma_f32_16x16x32_bf16(a[mm], vf[n][ks], acc[mm][n], 0, 0, 0);
      __builtin_amdgcn_s_setprio(0);
    }
    __syncthreads();
  }

  // ---- softmax denominator: in-wave shfl sums, wave owns rows [4g,4g+4) ----
#pragma unroll
  for (int sh = 1; sh < 64; sh <<= 1){
    lp0 += __shfl_xor(lp0, sh);
    lp1 += __shfl_xor(lp1, sh);
    lp2 += __shfl_xor(lp2, sh);
    lp3 += __shfl_xor(lp3, sh);
  }
  if (lane == 0){
    fin[g * 4 + 0] = 1.f / lp0;
    fin[g * 4 + 1] = 1.f / lp1;
    fin[g * 4 + 2] = 1.f / lp2;
    fin[g * 4 + 3] = 1.f / lp3;
  }
  __syncthreads();

  // ---- epilogue: 4 rounds of 16 rows x 512 cols via LDS transpose (img overlays Klds) ----
  float* img = (float*)smem;
#pragma unroll
  for (int mm = 0; mm < 4; ++mm){
    float linv[4];
#pragma unroll
    for (int j = 0; j < 4; ++j)
      linv[j] = fin[mm * 16 + ((lane >> 4) << 2) + j];
#pragma unroll
    for (int n = 0; n < 2; ++n){
      int colL = g * 32 + n * 16 + (lane & 15);
#pragma unroll
      for (int j = 0; j < 4; ++j){
        int r16 = ((lane >> 4) << 2) + j;
        img[r16 * 520 + colL] = acc[mm][n][j] * linv[j];
      }
    }
    __syncthreads();
#pragma unroll
    for (int i = 0; i < 2; ++i){
      int f4 = i * 1024 + t;
      int r16 = f4 >> 7, c4 = f4 & 127;
      float4 v = *(const float4*)(img + r16 * 520 + c4 * 4);
      *(float4*)(Out + (size_t)(b * 2048 + qbase + mm * 16 + r16) * 512 + c4 * 4) = v;
    }
    __syncthreads();
  }
}

extern "C" void kernel_launch(void* const* d_in, const int* in_sizes, int n_in,
                              void* d_out, int out_size, void* d_ws, size_t ws_size,
                              hipStream_t stream){
  const float* In = (const float*)d_in[0];
  const float* Wq = (const float*)d_in[1];
  const float* Wk = (const float*)d_in[2];
  const float* Wv = (const float*)d_in[3];
  // power (d_in[4]) is the constant 8; hardcoded as three squarings.
  char* ws = (char*)d_ws;
  unsigned short* WvT = (unsigned short*)(ws);
  float* Q            = (float*)(ws + 524288);
  float* Kt           = (float*)(ws + 1048576);
  unsigned short* Vg  = (unsigned short*)(ws + 1572864);
  float* Out = (float*)d_out;

  hipLaunchKernelGGL(k_wvT,   dim3(64),   dim3(256),  0, stream, Wv, WvT);
  hipLaunchKernelGGL(k_fused, dim3(1536), dim3(256),  0, stream, In, Wq, Wk, WvT, Q, Kt, Vg);
  hipLaunchKernelGGL(k_attn,  dim3(256),  dim3(1024), 0, stream, Q, Kt, Vg, Out);
}